// Round 6
// baseline (545.007 us; speedup 1.0000x reference)
//
#include <hip/hip_runtime.h>
#include <hip/hip_bf16.h>
#include <stdint.h>

#define NB   4096
#define NTOK 16
#define ND   256
#define NS   256
#define NL   4
#define KIN  1056
#define RMS_EPS 1e-4f

typedef float f32x4 __attribute__((ext_vector_type(4)));
typedef short s16x8 __attribute__((ext_vector_type(8)));

__device__ __forceinline__ unsigned short f2bf(float f) {
    unsigned u = __float_as_uint(f);
    u += 0x7fff + ((u >> 16) & 1);          // RNE
    return (unsigned short)(u >> 16);
}

// ---------------- prep kernels ----------------

// all 4 weight casts in one launch; dst = [W0bf][Winbf][Woutbf][Wskipbf] contiguous
__global__ __launch_bounds__(256) void k_cast4(const float* __restrict__ W0,
                                               const float* __restrict__ Wi,
                                               const float* __restrict__ Wo,
                                               const float* __restrict__ Ws,
                                               unsigned short* __restrict__ dst) {
    const int n0 = 256 * KIN;          // 270336
    const int nw = NL * 65536;         // 262144
    const int total = n0 + 3 * nw;
    for (int i = blockIdx.x * blockDim.x + threadIdx.x; i < total; i += gridDim.x * blockDim.x) {
        float v;
        if (i < n0) v = W0[i];
        else {
            int j = i - n0;
            v = (j < nw) ? Wi[j] : (j < 2 * nw ? Wo[j - nw] : Ws[j - 2 * nw]);
        }
        dst[i] = f2bf(v);
    }
}

__global__ __launch_bounds__(256) void k_build_a0(const float* __restrict__ stoch,
                                                  const float* __restrict__ act,
                                                  unsigned short* __restrict__ a0) {
    int total = NB * KIN;
    for (int i = blockIdx.x * blockDim.x + threadIdx.x; i < total; i += gridDim.x * blockDim.x) {
        int b = i / KIN, k = i - b * KIN;
        float v;
        if (k < 1024) v = stoch[b * 1024 + k];
        else { float a = act[b * 32 + (k - 1024)]; v = a / fmaxf(fabsf(a), 1.0f); }
        a0[i] = f2bf(v);
    }
}

// ---------------- input-proj GEMM (K=1056) ----------------
#define KP 40
__device__ __forceinline__ void gemm_chunked(const unsigned short* __restrict__ A,
                                             const unsigned short* __restrict__ W,
                                             int K, int m0, int n0,
                                             unsigned short* lds, f32x4 acc[4][2]) {
    const int tid = threadIdx.x;
    const int lane = tid & 63;
    const int wvid = tid >> 6;
    const int wm = wvid & 1, wn = wvid >> 1;
    const int srow = tid >> 2, skk = (tid & 3) * 8;
    const int mbase = m0 + wm * 64 + (lane & 15);
    const int koff = (lane >> 4) * 8;
    const int brow = wn * 32 + (lane & 15);
    for (int kc = 0; kc < K; kc += 32) {
        __syncthreads();
        *reinterpret_cast<s16x8*>(&lds[srow * KP + skk]) =
            *reinterpret_cast<const s16x8*>(&W[(size_t)(n0 + srow) * K + kc + skk]);
        __syncthreads();
        s16x8 a[4];
#pragma unroll
        for (int mf = 0; mf < 4; mf++)
            a[mf] = *reinterpret_cast<const s16x8*>(&A[(size_t)(mbase + mf * 16) * K + kc + koff]);
#pragma unroll
        for (int nf = 0; nf < 2; nf++) {
            s16x8 bfr = *reinterpret_cast<const s16x8*>(&lds[(brow + nf * 16) * KP + koff]);
#pragma unroll
            for (int mf = 0; mf < 4; mf++)
                acc[mf][nf] = __builtin_amdgcn_mfma_f32_16x16x32_bf16(a[mf], bfr, acc[mf][nf], 0, 0, 0);
        }
    }
}

__global__ __launch_bounds__(256) void k_gemm_h(const unsigned short* __restrict__ A0,
                                                const unsigned short* __restrict__ W0bf,
                                                const float* __restrict__ b0,
                                                float* __restrict__ h) {
    __shared__ unsigned short lds[64 * KP];
    f32x4 acc[4][2];
#pragma unroll
    for (int i = 0; i < 4; i++)
#pragma unroll
        for (int j = 0; j < 2; j++) acc[i][j] = (f32x4){0.f, 0.f, 0.f, 0.f};
    int m0 = blockIdx.x * 128, n0 = blockIdx.y * 64;
    gemm_chunked(A0, W0bf, KIN, m0, n0, lds, acc);
    int lane = threadIdx.x & 63, wvid = threadIdx.x >> 6;
    int wm = wvid & 1, wn = wvid >> 1;
    int rbase = m0 + wm * 64 + (lane >> 4) * 4;
    int cbase = n0 + wn * 32 + (lane & 15);
#pragma unroll
    for (int mf = 0; mf < 4; mf++)
#pragma unroll
        for (int nf = 0; nf < 2; nf++) {
            int col = cbase + nf * 16;
            float bb = b0[col];
#pragma unroll
            for (int r = 0; r < 4; r++)
                h[(size_t)(rbase + mf * 16 + r) * ND + col] = acc[mf][nf][r] + bb;
        }
}

// rms + silu -> ntok (contiguous fp32 [4096][256])
__global__ __launch_bounds__(256) void k_h_norm(const float* __restrict__ X,
                                                const float* __restrict__ wg,
                                                float* __restrict__ ntok) {
    int row = blockIdx.x * 4 + (threadIdx.x >> 6);
    int lane = threadIdx.x & 63;
    float4 v = reinterpret_cast<const float4*>(X)[(size_t)row * 64 + lane];
    float ss = v.x * v.x + v.y * v.y + v.z * v.z + v.w * v.w;
#pragma unroll
    for (int off = 32; off > 0; off >>= 1) ss += __shfl_xor(ss, off);
    float scale = rsqrtf(ss * (1.0f / 256.0f) + RMS_EPS);
    float4 wv = reinterpret_cast<const float4*>(wg)[lane];
    float o0 = v.x * scale * wv.x, o1 = v.y * scale * wv.y;
    float o2 = v.z * scale * wv.z, o3 = v.w * scale * wv.w;
    float4 qq;
    qq.x = o0 / (1.f + expf(-o0));
    qq.y = o1 / (1.f + expf(-o1));
    qq.z = o2 / (1.f + expf(-o2));
    qq.w = o3 / (1.f + expf(-o3));
    reinterpret_cast<float4*>(ntok)[(size_t)row * 64 + lane] = qq;
}

// ---------------- persistent mega-kernel (v3) ----------------
// 256 thr = 4 waves. Block owns 2 batch rows (M = 32 token-rows), all layers.
// Wave w owns output cols [w*64, w*64+64): tok[mf][nf] f32x4, mf in {0,1}, nf in {0..3}.
//   tok[mf][nf][r] = row (mf*16 + g*4 + r), col (w*64 + nf*16 + q)
// Small footprint (LDS ~17 KB, VGPR ~100) -> many independent block contexts
// per CU; lockstep-block stalls interleave across blocks (round-5 lesson).
// ONE shared A-tile xs[32][264]: x for skip/u GEMMs, then states for out GEMM.

#define LSTR 264

__global__ __launch_bounds__(256, 4) void k_mega(
    const float* __restrict__ deter, const float* __restrict__ ntok,
    const unsigned short* __restrict__ Win, const unsigned short* __restrict__ Wout,
    const unsigned short* __restrict__ Wskip,
    const float* __restrict__ norm_w, const float* __restrict__ b_in,
    const float* __restrict__ b_out, const float* __restrict__ b_skip,
    const float* __restrict__ log_dec, const float* __restrict__ out_nw,
    float* __restrict__ out)
{
    __shared__ __align__(16) unsigned short xs[32 * LSTR];   // 16896 B
    __shared__ __align__(16) float red[4 * 32 + 32];         // 640 B

    const int tid = threadIdx.x;
    const int lane = tid & 63;
    const int w = tid >> 6;          // 0..3 -> col window w*64
    const int g = lane >> 4;
    const int q = lane & 15;
    const int b0 = blockIdx.x * 2;
    const int lm16 = (lane - 16) & 63, lm32 = (lane - 32) & 63, lm48 = (lane - 48) & 63;

    f32x4 tok[2][4];
    // ---- entry: shifted deter tokens + new token ----
#pragma unroll
    for (int mf = 0; mf < 2; mf++) {
        const float* dbase = deter + (size_t)(b0 + mf) * 4096;
        const float* nbase = ntok + (size_t)(b0 + mf) * 256;
#pragma unroll
        for (int nf = 0; nf < 4; nf++) {
            int col = w * 64 + nf * 16 + q;
#pragma unroll
            for (int r = 0; r < 4; r++) {
                int t = g * 4 + r;
                tok[mf][nf][r] = (t < 15) ? dbase[(t + 1) * 256 + col] : nbase[col];
            }
        }
    }

    float scale[2][4];

    auto rms_scale = [&]() {
#pragma unroll
        for (int mf = 0; mf < 2; mf++) {
            f32x4 p;
#pragma unroll
            for (int r = 0; r < 4; r++)
                p[r] = tok[mf][0][r] * tok[mf][0][r] + tok[mf][1][r] * tok[mf][1][r]
                     + tok[mf][2][r] * tok[mf][2][r] + tok[mf][3][r] * tok[mf][3][r];
#pragma unroll
            for (int mask = 1; mask < 16; mask <<= 1) {
#pragma unroll
                for (int r = 0; r < 4; r++) p[r] += __shfl_xor(p[r], mask);
            }
            if (q == 0) *reinterpret_cast<f32x4*>(&red[w * 32 + mf * 16 + g * 4]) = p;
        }
        __syncthreads();
        if (tid < 32) {
            float s = red[tid] + red[32 + tid] + red[64 + tid] + red[96 + tid];
            red[128 + tid] = rsqrtf(s * (1.0f / 256.0f) + RMS_EPS);
        }
        __syncthreads();
#pragma unroll
        for (int mf = 0; mf < 2; mf++) {
            f32x4 sc = *reinterpret_cast<const f32x4*>(&red[128 + mf * 16 + g * 4]);
#pragma unroll
            for (int r = 0; r < 4; r++) scale[mf][r] = sc[r];
        }
    };

    // GEMM over the shared A-tile; accumulates into acc IN PLACE.
    auto gemm = [&](const unsigned short* __restrict__ Bmat, f32x4 acc[2][4]) {
        const unsigned short* bp = Bmat + (size_t)(w * 64 + q) * 256 + g * 8;
        const unsigned short* ap = xs + q * LSTR + g * 8;
#pragma unroll 2
        for (int kc = 0; kc < 256; kc += 32) {
            s16x8 bw[4];
#pragma unroll
            for (int nf = 0; nf < 4; nf++)
                bw[nf] = *reinterpret_cast<const s16x8*>(bp + nf * (16 * 256) + kc);
#pragma unroll
            for (int mf = 0; mf < 2; mf++) {
                s16x8 a = *reinterpret_cast<const s16x8*>(ap + mf * (16 * LSTR) + kc);
#pragma unroll
                for (int nf = 0; nf < 4; nf++)
                    acc[mf][nf] = __builtin_amdgcn_mfma_f32_16x16x32_bf16(a, bw[nf], acc[mf][nf], 0, 0, 0);
            }
        }
    };

    for (int l = 0; l < NL; l++) {
        const unsigned short* Wi = Win + (size_t)l * 65536;
        const unsigned short* Wo = Wout + (size_t)l * 65536;
        const unsigned short* Ws = Wskip + (size_t)l * 65536;
        float nw[4], bi[4], dec[4], bo[4];
#pragma unroll
        for (int nf = 0; nf < 4; nf++) {
            int col = w * 64 + nf * 16 + q;
            nw[nf] = norm_w[l * 256 + col];
            bi[nf] = b_in[l * 256 + col];
            dec[nf] = 1.f / (1.f + expf(-log_dec[l * 256 + col]));
            bo[nf] = b_out[l * 256 + col] + b_skip[l * 256 + col];
        }

        rms_scale();   // 2 barriers: also protects xs from previous layer's reads
        // x = rms(tok)*nw -> xs  (direct b16 stores)
#pragma unroll
        for (int mf = 0; mf < 2; mf++)
#pragma unroll
            for (int r = 0; r < 4; r++) {
                int m = mf * 16 + g * 4 + r;
#pragma unroll
                for (int nf = 0; nf < 4; nf++)
                    xs[m * LSTR + w * 64 + nf * 16 + q] = f2bf(tok[mf][nf][r] * scale[mf][r] * nw[nf]);
            }
        __syncthreads();

        // skip GEMM: tok += x @ Wskip^T   (in-place C accumulate)
        gemm(Ws, tok);

        // u GEMM: acc = x @ Win^T
        f32x4 acc[2][4];
#pragma unroll
        for (int i = 0; i < 2; i++)
#pragma unroll
            for (int j = 0; j < 4; j++) acc[i][j] = (f32x4){0.f, 0.f, 0.f, 0.f};
        gemm(Wi, acc);

        // bias + in-register decay scan over t = g*4+r
#pragma unroll
        for (int mf = 0; mf < 2; mf++)
#pragma unroll
            for (int nf = 0; nf < 4; nf++) {
                float d1 = dec[nf], dd2 = d1 * d1, dd3 = dd2 * d1, dd4 = dd2 * dd2, dd8 = dd4 * dd4;
                f32x4& u = acc[mf][nf];
                float s0 = u[0] + bi[nf];
                float s1 = u[1] + bi[nf] + d1 * s0;
                float s2 = u[2] + bi[nf] + d1 * s1;
                float s3 = u[3] + bi[nf] + d1 * s2;
                float Q = s3;
                float q1 = __shfl(Q, lm16); q1 = (g >= 1) ? q1 : 0.f;
                float q2 = __shfl(Q, lm32); q2 = (g >= 2) ? q2 : 0.f;
                float q3 = __shfl(Q, lm48); q3 = (g >= 3) ? q3 : 0.f;
                float carry = q1 + dd4 * q2 + dd8 * q3;
                u[0] = s0 + d1 * carry;
                u[1] = s1 + dd2 * carry;
                u[2] = s2 + dd3 * carry;
                u[3] = s3 + dd4 * carry;
            }

        __syncthreads();   // all waves done reading xs (skip+u GEMMs)
        // states -> xs (overwrite)
#pragma unroll
        for (int mf = 0; mf < 2; mf++)
#pragma unroll
            for (int r = 0; r < 4; r++) {
                int m = mf * 16 + g * 4 + r;
#pragma unroll
                for (int nf = 0; nf < 4; nf++)
                    xs[m * LSTR + w * 64 + nf * 16 + q] = f2bf(acc[mf][nf][r]);
            }
        __syncthreads();

        // out GEMM: tok += states @ Wout^T  (in place), then biases
        gemm(Wo, tok);
#pragma unroll
        for (int mf = 0; mf < 2; mf++)
#pragma unroll
            for (int nf = 0; nf < 4; nf++)
#pragma unroll
                for (int r = 0; r < 4; r++)
                    tok[mf][nf][r] += bo[nf];
    }

    // final rmsnorm -> fp32 out
    rms_scale();
    float onw[4];
#pragma unroll
    for (int nf = 0; nf < 4; nf++) onw[nf] = out_nw[w * 64 + nf * 16 + q];
#pragma unroll
    for (int mf = 0; mf < 2; mf++) {
        float* obase = out + (size_t)(b0 + mf) * 4096;
#pragma unroll
        for (int r = 0; r < 4; r++)
#pragma unroll
            for (int nf = 0; nf < 4; nf++)
                obase[(g * 4 + r) * 256 + w * 64 + nf * 16 + q] =
                    tok[mf][nf][r] * scale[mf][r] * onw[nf];
    }
}

// ---------------- launch ----------------

extern "C" void kernel_launch(void* const* d_in, const int* in_sizes, int n_in,
                              void* d_out, int out_size, void* d_ws, size_t ws_size,
                              hipStream_t stream) {
    const float* stoch   = (const float*)d_in[0];
    const float* deter   = (const float*)d_in[1];
    const float* action  = (const float*)d_in[2];
    const float* W0      = (const float*)d_in[3];
    const float* b0      = (const float*)d_in[4];
    const float* g0      = (const float*)d_in[5];
    const float* norm_w  = (const float*)d_in[6];
    const float* W_in    = (const float*)d_in[7];
    const float* b_in    = (const float*)d_in[8];
    const float* W_out   = (const float*)d_in[9];
    const float* b_out   = (const float*)d_in[10];
    const float* W_skip  = (const float*)d_in[11];
    const float* b_skip  = (const float*)d_in[12];
    const float* log_dec = (const float*)d_in[13];
    const float* onw     = (const float*)d_in[14];
    float* out = (float*)d_out;

    unsigned short* A0bf    = (unsigned short*)d_ws;                  // NB*KIN
    unsigned short* W0bf    = A0bf + (size_t)NB * KIN;                // 256*KIN
    unsigned short* Winbf   = W0bf + (size_t)256 * KIN;               // NL*65536
    unsigned short* Woutbf  = Winbf + (size_t)NL * 65536;
    unsigned short* Wskipbf = Woutbf + (size_t)NL * 65536;
    float* hbuf = (float*)(Wskipbf + (size_t)NL * 65536);             // NB*256
    float* ntok = hbuf + (size_t)NB * 256;                            // NB*256

    k_cast4<<<1024, 256, 0, stream>>>(W0, W_in, W_out, W_skip, W0bf);
    k_build_a0<<<2048, 256, 0, stream>>>(stoch, action, A0bf);

    k_gemm_h<<<dim3(NB / 128, 4), 256, 0, stream>>>(A0bf, W0bf, b0, hbuf);
    k_h_norm<<<NB / 4, 256, 0, stream>>>(hbuf, g0, ntok);

    k_mega<<<2048, 256, 0, stream>>>(deter, ntok, Winbf, Woutbf, Wskipbf,
                                     norm_w, b_in, b_out, b_skip, log_dec, onw, out);
}